// Round 16
// baseline (74.659 us; speedup 1.0000x reference)
//
#include <hip/hip_runtime.h>
#include <hip/hip_bf16.h>

#define Bn 4096
#define Ln 512
#define Hn 32
#define MT 4  // m-tiles per block (grid = 128 bn x 8 mg)

using bf16x8 = __attribute__((ext_vector_type(8))) __bf16;
using f32x4  = __attribute__((ext_vector_type(4))) float;

#define GLOAD_LDS16(g, l)                                                          \
  __builtin_amdgcn_global_load_lds(                                                \
      (const __attribute__((address_space(1))) void*)(g),                          \
      (__attribute__((address_space(3))) void*)(l), 16, 0, 0)

__device__ __forceinline__ unsigned short f2bf(float x) {
  unsigned int u = __float_as_uint(x);
  unsigned int r = (u + 0x7FFFu + ((u >> 16) & 1u)) >> 16;
  return (unsigned short)r;
}

// Merged prep: blocks [0,8192) convert W1 f32->bf16 (zero-filling masked
// upper-triangular groups, reading only ~half); blocks [8192,16384) build V.
__global__ __launch_bounds__(256) void prep_kernel(
    const float* __restrict__ W1, unsigned short* __restrict__ W1b,
    const float* __restrict__ mu, const float* __restrict__ log_var,
    const float* __restrict__ eps0, unsigned short* __restrict__ Vb) {
  const int bid = blockIdx.x;
  if (bid < 8192) {
    int idx = bid * 256 + threadIdx.x;        // float4 group index
    const int n  = idx >> 7;                  // row in [0, 16384)
    const int c0 = (idx & 127) * 4;           // first col of group
    const int i  = n >> 5;                    // latent step of this row
    ushort4 o;
    if (c0 > i) {
      o.x = 0; o.y = 0; o.z = 0; o.w = 0;     // fully-masked group
    } else {
      const float4 f = reinterpret_cast<const float4*>(W1)[idx];
      o.x = f2bf(f.x); o.y = f2bf(f.y); o.z = f2bf(f.z); o.w = f2bf(f.w);
    }
    reinterpret_cast<ushort4*>(W1b)[idx] = o;
  } else {
    int idx = (bid - 8192) * 256 + threadIdx.x;  // B*L threads
    int b = idx >> 9, j = idx & 511;
    float v;
    if (j == 0) {
      v = eps0[b] * __builtin_exp2f(log_var[(size_t)b * Ln] * 0.7213475204444817f)
          + mu[(size_t)b * Ln];
    } else {
      v = mu[(size_t)b * Ln + j - 1];
    }
    Vb[idx] = f2bf(v);
  }
}

// Fused: Hm = leaky_relu(V @ W1^T + b1); out = Hm @ W2^T + b2; sample.
// R15 champion restructured to the T3-minimum SINGLE-BARRIER iteration:
//   { STAGE(next) issue -> COMPUTE(cur) -> [epilogue] -> vmcnt(0) -> barrier }
// The full drain overlaps COMPUTE (~600-800cyc >= L2-hit latency); one
// barrier per iteration instead of two (18432 fewer). Safety: buf was
// drained+barriered at end of iter t-1; STAGE(t+1) writes buf^1 whose
// readers (COMPUTE at t-1) all passed that barrier.
// + T5 s_setprio(1) around the MFMA cluster (2 independent blocks/CU give
//   the wave role diversity where setprio pays).
// Keeps: balanced group-of-4 XCD pairing, hoisted block-constant weights,
// separate Sx scratch, LDS-transposed float4 output, zero-fill prep.
__global__ __launch_bounds__(256) void gemm_fused_kernel(
    const unsigned short* __restrict__ Vb,   // [4096,512] bf16
    const unsigned short* __restrict__ W1b,  // [16384,512] bf16
    const float* __restrict__ b1,            // [512,32]
    const float* __restrict__ W2,            // [512,2,32]
    const float* __restrict__ b2,            // [512,2]
    const float* __restrict__ eps,           // [4096,512]
    float* __restrict__ out)                 // [3, 4096, 512]
{
  const int tid  = threadIdx.x;
  const int wid  = tid >> 6;
  const int lane = tid & 63;
  const int l15  = lane & 15;
  const int lq   = lane >> 4;

  // ---- balanced group-of-4 XCD striping (heavy-first within each XCD).
  // Group g has ksteps = floor(g/4)+1; XCD x gets {31-x, 23-x, 8+x, x}
  // -> per-XCD ksteps sum = 18 exactly.
  const int bid  = blockIdx.x;
  const int xcd  = bid & 7;
  const int s    = bid >> 3;              // 0..127
  const int sel  = s >> 5;                // 0..3, dispatch order = heavy first
  int g;
  switch (sel) {
    case 0:  g = 31 - xcd; break;
    case 1:  g = 23 - xcd; break;
    case 2:  g = 8 + xcd;  break;
    default: g = xcd;      break;
  }
  const int bn   = g * 4 + ((s >> 3) & 3);
  const int mg   = s & 7;
  const int mb   = mg * (MT * 128);
  const int nb   = bn * 128;

  // triangular cutoff: block's i in [bn*4, bn*4+3] -> j <= bn*4+3
  const int ksteps = min(8, (bn + 16) >> 4);  // ceil((4bn+4)/64)

  __shared__ unsigned short As[2 * 128 * 64];  // 2 x 16 KiB
  __shared__ unsigned short Bs[2 * 128 * 64];  // 2 x 16 KiB
  __shared__ float          Sx[1024];          // 4 KiB epilogue scratch

  // ---- staging: chunk = 8 rows x 128 B; lane -> (row=lane>>3, slot=lane&7).
  // LDS linear slot (row, s) receives global element (row, s ^ row) [16B slots].
  const int rowc = lane >> 3;
  const int sswz = (lane & 7) ^ rowc;
  const unsigned short* gA = Vb  + (size_t)(mb + wid * 32 + rowc) * Ln + sswz * 8;
  const unsigned short* gB = W1b + (size_t)(nb + wid * 32 + rowc) * Ln + sswz * 8;
  unsigned short* lA = As + wid * 2048;
  unsigned short* lB = Bs + wid * 2048;

  auto STAGE = [&](int bufw, int mt_, int k0e) {  // 8 VMEM ops per wave
    const int    lofs = bufw * 8192;
    const size_t ga   = (size_t)mt_ * (128 * Ln) + k0e;
#pragma unroll
    for (int j = 0; j < 4; ++j) {
      GLOAD_LDS16(gA + ga + (size_t)j * 8 * Ln, lA + lofs + j * 512);
      GLOAD_LDS16(gB + k0e + (size_t)j * 8 * Ln, lB + lofs + j * 512);
    }
  };

  // ---- hoisted epilogue constants (block-fixed; free at 2 blocks/CU).
  int zero;
  asm volatile("v_mov_b32 %0, 0" : "=v"(zero));
  float4 b1q[2][2], w20q[2][2], w21q[2][2], b2q;
#pragma unroll
  for (int il = 0; il < 2; ++il) {
    const int i = bn * 4 + (wid & 1) * 2 + il;
#pragma unroll
    for (int q = 0; q < 2; ++q) {  // 12 x dwordx4
      const int hb = q * 16 + lq * 4 + zero;
      b1q[il][q]  = *reinterpret_cast<const float4*>(b1 + i * Hn + hb);
      w20q[il][q] = *reinterpret_cast<const float4*>(W2 + (i * 2 + 0) * Hn + hb);
      w21q[il][q] = *reinterpret_cast<const float4*>(W2 + (i * 2 + 1) * Hn + hb);
    }
  }
  b2q = *reinterpret_cast<const float4*>(b2 + (bn * 4 + (wid & 1) * 2) * 2 + zero);

  // ---- fragment reads: row = base + l15 (+f*16); linear slot = (ks2*4+lq) ^ (row&7)
  const int arow = (wid >> 1) * 64 + l15;
  const int brow = (wid & 1) * 64 + l15;
  const int swz7 = l15 & 7;

  f32x4 acc[4][4];  // acc[fn][fm]: rows = n-side (i,h), cols = batch
#pragma unroll
  for (int fn = 0; fn < 4; ++fn)
#pragma unroll
    for (int fm = 0; fm < 4; ++fm) acc[fn][fm] = f32x4{0.f, 0.f, 0.f, 0.f};

  auto COMPUTE = [&](int bufc) {
    const int cofs = bufc * 8192;
    __builtin_amdgcn_s_setprio(1);  // favor this wave while MFMA cluster runs
#pragma unroll
    for (int ks2 = 0; ks2 < 2; ++ks2) {
      const int se = ((ks2 * 4 + lq) ^ swz7) * 8;
      bf16x8 a[4], b[4];
#pragma unroll
      for (int f = 0; f < 4; ++f) {
        a[f] = *reinterpret_cast<const bf16x8*>(As + cofs + (arow + f * 16) * 64 + se);
        b[f] = *reinterpret_cast<const bf16x8*>(Bs + cofs + (brow + f * 16) * 64 + se);
      }
#pragma unroll
      for (int fn = 0; fn < 4; ++fn)
#pragma unroll
        for (int fm = 0; fm < 4; ++fm)
          acc[fn][fm] = __builtin_amdgcn_mfma_f32_16x16x32_bf16(b[fn], a[fm],
                                                                acc[fn][fm], 0, 0, 0);
    }
    __builtin_amdgcn_s_setprio(0);
  };

  float* mus = out;
  float* lvs = out + (size_t)Bn * Ln;
  float* smp = out + (size_t)2 * Bn * Ln;

  // prologue: first tile staged + drained
  int buf = 0;
  STAGE(0, 0, 0);
  asm volatile("s_waitcnt vmcnt(0)" ::: "memory");
  __builtin_amdgcn_s_barrier();

  for (int mt = 0; mt < MT; ++mt) {
    for (int k = 0; k < ksteps; ++k) {
      int kn = k + 1, mtn = mt;
      if (kn == ksteps) { kn = 0; ++mtn; }
      const bool epi  = (k == ksteps - 1);
      const bool more = (mtn < MT);

      // issue next tile's prefetch FIRST -- it drains at this iter's end,
      // overlapped with COMPUTE (+ epilogue on epi iters)
      if (more) STAGE(buf ^ 1, mtn, kn * 64);

      float4 ep4;
      if (epi) {  // eps pre-load: overlaps COMPUTE; compiler-waited at use
        const size_t eo = (size_t)(mb + mt * 128 + (tid & 127)) * Ln + bn * 4;
        ep4 = *reinterpret_cast<const float4*>(eps + eo + zero);
      }
      __builtin_amdgcn_sched_barrier(0);  // pin issue window above COMPUTE

      COMPUTE(buf);

      if (epi) {
        // ======== per-m-tile epilogue: own scratch, one internal barrier ====
        const int wrow = (wid >> 1) * 64;
#pragma unroll
        for (int il = 0; il < 2; ++il) {
          const int   icl   = (wid & 1) * 2 + il;
          const float bias0 = (il == 0) ? b2q.x : b2q.z;
          const float bias1 = (il == 0) ? b2q.y : b2q.w;
#pragma unroll
          for (int fm = 0; fm < 4; ++fm) {
            float p0 = 0.f, p1 = 0.f;
#pragma unroll
            for (int q = 0; q < 2; ++q) {
              const f32x4& A = acc[il * 2 + q][fm];
              const float* b1f = reinterpret_cast<const float*>(&b1q[il][q]);
              const float* w0f = reinterpret_cast<const float*>(&w20q[il][q]);
              const float* w1f = reinterpret_cast<const float*>(&w21q[il][q]);
#pragma unroll
              for (int r = 0; r < 4; ++r) {
                float x  = A[r] + b1f[r];
                float hv = fmaxf(x, 0.01f * x);  // leaky_relu (slope 0.01)
                p0 += hv * w0f[r];
                p1 += hv * w1f[r];
              }
            }
            p0 += __shfl_xor(p0, 16);
            p0 += __shfl_xor(p0, 32);
            p1 += __shfl_xor(p1, 16);
            p1 += __shfl_xor(p1, 32);
            if (lq == 0) {
              const int r = wrow + fm * 16 + l15;
              Sx[icl * 128 + r]       = p0 + bias0;
              Sx[512 + icl * 128 + r] = p1 + bias1;
            }
          }
        }
        asm volatile("s_waitcnt lgkmcnt(0)" ::: "memory");  // Sx writes done
        __builtin_amdgcn_s_barrier();                        // Sx visible

        if (tid < 128) {  // wave-uniform: waves 0,1 active
          const int    r = tid;
          const size_t o = (size_t)(mb + mt * 128 + r) * Ln + bn * 4;
          float4 muv, lvv;
          muv.x = Sx[r];       muv.y = Sx[128 + r]; muv.z = Sx[256 + r]; muv.w = Sx[384 + r];
          lvv.x = Sx[512 + r]; lvv.y = Sx[640 + r]; lvv.z = Sx[768 + r]; lvv.w = Sx[896 + r];
          float4 sm;
          sm.x = ep4.x * __builtin_exp2f(lvv.x * 0.7213475204444817f) + muv.x;
          sm.y = ep4.y * __builtin_exp2f(lvv.y * 0.7213475204444817f) + muv.y;
          sm.z = ep4.z * __builtin_exp2f(lvv.z * 0.7213475204444817f) + muv.z;
          sm.w = ep4.w * __builtin_exp2f(lvv.w * 0.7213475204444817f) + muv.w;
          *reinterpret_cast<float4*>(mus + o) = muv;
          *reinterpret_cast<float4*>(lvs + o) = lvv;
          *reinterpret_cast<float4*>(smp + o) = sm;
        }
        // reset accumulators for the next m-tile
#pragma unroll
        for (int fn = 0; fn < 4; ++fn)
#pragma unroll
          for (int fm = 0; fm < 4; ++fm) acc[fn][fm] = f32x4{0.f, 0.f, 0.f, 0.f};
      }

      // single end-of-iter sync: prefetch landed (vmcnt 0) AND all waves'
      // reads of buf are done -> next iter may read buf^1 and overwrite buf
      asm volatile("s_waitcnt vmcnt(0)" ::: "memory");
      __builtin_amdgcn_s_barrier();
      buf ^= 1;
    }
  }
}

extern "C" void kernel_launch(void* const* d_in, const int* in_sizes, int n_in,
                              void* d_out, int out_size, void* d_ws, size_t ws_size,
                              hipStream_t stream) {
  const float* mu      = (const float*)d_in[0];
  const float* log_var = (const float*)d_in[1];
  const float* eps0    = (const float*)d_in[2];
  const float* eps     = (const float*)d_in[3];
  const float* W1      = (const float*)d_in[4];
  const float* b1      = (const float*)d_in[5];
  const float* W2      = (const float*)d_in[6];
  const float* b2      = (const float*)d_in[7];
  float* out = (float*)d_out;

  unsigned short* Vb  = (unsigned short*)d_ws;                                  // 4 MiB
  unsigned short* W1b = (unsigned short*)((char*)d_ws + (size_t)Bn * Ln * 2);   // 16 MiB

  prep_kernel<<<16384, 256, 0, stream>>>(W1, W1b, mu, log_var, eps0, Vb);
  gemm_fused_kernel<<<128 * (32 / MT), 256, 0, stream>>>(
      Vb, W1b, b1, W2, b2, eps, out);
}

// Round 17
// 73.180 us; speedup vs baseline: 1.0202x; 1.0202x over previous
//
#include <hip/hip_runtime.h>
#include <hip/hip_bf16.h>

#define Bn 4096
#define Ln 512
#define Hn 32
#define MT 4  // m-tiles per block (grid = 128 bn x 8 mg)

using bf16x8 = __attribute__((ext_vector_type(8))) __bf16;
using f32x4  = __attribute__((ext_vector_type(4))) float;

#define GLOAD_LDS16(g, l)                                                          \
  __builtin_amdgcn_global_load_lds(                                                \
      (const __attribute__((address_space(1))) void*)(g),                          \
      (__attribute__((address_space(3))) void*)(l), 16, 0, 0)

__device__ __forceinline__ unsigned short f2bf(float x) {
  unsigned int u = __float_as_uint(x);
  unsigned int r = (u + 0x7FFFu + ((u >> 16) & 1u)) >> 16;
  return (unsigned short)r;
}

// Merged prep: blocks [0,8192) convert W1 f32->bf16 (zero-filling masked
// upper-triangular groups, reading only ~half); blocks [8192,16384) build V.
__global__ __launch_bounds__(256) void prep_kernel(
    const float* __restrict__ W1, unsigned short* __restrict__ W1b,
    const float* __restrict__ mu, const float* __restrict__ log_var,
    const float* __restrict__ eps0, unsigned short* __restrict__ Vb) {
  const int bid = blockIdx.x;
  if (bid < 8192) {
    int idx = bid * 256 + threadIdx.x;        // float4 group index
    const int n  = idx >> 7;                  // row in [0, 16384)
    const int c0 = (idx & 127) * 4;           // first col of group
    const int i  = n >> 5;                    // latent step of this row
    ushort4 o;
    if (c0 > i) {
      o.x = 0; o.y = 0; o.z = 0; o.w = 0;     // fully-masked group
    } else {
      const float4 f = reinterpret_cast<const float4*>(W1)[idx];
      o.x = f2bf(f.x); o.y = f2bf(f.y); o.z = f2bf(f.z); o.w = f2bf(f.w);
    }
    reinterpret_cast<ushort4*>(W1b)[idx] = o;
  } else {
    int idx = (bid - 8192) * 256 + threadIdx.x;  // B*L threads
    int b = idx >> 9, j = idx & 511;
    float v;
    if (j == 0) {
      v = eps0[b] * __builtin_exp2f(log_var[(size_t)b * Ln] * 0.7213475204444817f)
          + mu[(size_t)b * Ln];
    } else {
      v = mu[(size_t)b * Ln + j - 1];
    }
    Vb[idx] = f2bf(v);
  }
}

// Fused: Hm = leaky_relu(V @ W1^T + b1); out = Hm @ W2^T + b2; sample.
// R15 CHAMPION (verbatim revert; R16's single-barrier+setprio bundle
// regressed 2% -- full vmcnt(0) drain per iter gave up T4's counted wait).
// Structure: BK=64, MT=4, both operands global_load_lds, double-buffered,
// counted vmcnt(8)/vmcnt(9)/vmcnt(1), 2 barriers/iter, balanced group-of-4
// XCD pairing (per-XCD ksteps sum = 18 exactly), block-constant b1/W2/b2
// hoisted to registers, separate Sx scratch, barrier-free epilogue with
// LDS-transposed float4 output, eps pre-window older than the prefetch.
__global__ __launch_bounds__(256) void gemm_fused_kernel(
    const unsigned short* __restrict__ Vb,   // [4096,512] bf16
    const unsigned short* __restrict__ W1b,  // [16384,512] bf16
    const float* __restrict__ b1,            // [512,32]
    const float* __restrict__ W2,            // [512,2,32]
    const float* __restrict__ b2,            // [512,2]
    const float* __restrict__ eps,           // [4096,512]
    float* __restrict__ out)                 // [3, 4096, 512]
{
  const int tid  = threadIdx.x;
  const int wid  = tid >> 6;
  const int lane = tid & 63;
  const int l15  = lane & 15;
  const int lq   = lane >> 4;

  // ---- balanced group-of-4 XCD striping (heavy-first within each XCD).
  // Group g has ksteps = floor(g/4)+1; XCD x gets {31-x, 23-x, 8+x, x}
  // -> per-XCD ksteps sum = 18 exactly (R14: removed the 25% XCD7 tail).
  const int bid  = blockIdx.x;
  const int xcd  = bid & 7;
  const int s    = bid >> 3;              // 0..127
  const int sel  = s >> 5;                // 0..3, dispatch order = heavy first
  int g;
  switch (sel) {
    case 0:  g = 31 - xcd; break;
    case 1:  g = 23 - xcd; break;
    case 2:  g = 8 + xcd;  break;
    default: g = xcd;      break;
  }
  const int bn   = g * 4 + ((s >> 3) & 3);
  const int mg   = s & 7;
  const int mb   = mg * (MT * 128);
  const int nb   = bn * 128;

  // triangular cutoff: block's i in [bn*4, bn*4+3] -> j <= bn*4+3
  const int ksteps = min(8, (bn + 16) >> 4);  // ceil((4bn+4)/64)

  __shared__ unsigned short As[2 * 128 * 64];  // 2 x 16 KiB
  __shared__ unsigned short Bs[2 * 128 * 64];  // 2 x 16 KiB
  __shared__ float          Sx[1024];          // 4 KiB epilogue scratch

  // ---- staging: chunk = 8 rows x 128 B; lane -> (row=lane>>3, slot=lane&7).
  // LDS linear slot (row, s) receives global element (row, s ^ row) [16B slots].
  const int rowc = lane >> 3;
  const int sswz = (lane & 7) ^ rowc;
  const unsigned short* gA = Vb  + (size_t)(mb + wid * 32 + rowc) * Ln + sswz * 8;
  const unsigned short* gB = W1b + (size_t)(nb + wid * 32 + rowc) * Ln + sswz * 8;
  unsigned short* lA = As + wid * 2048;
  unsigned short* lB = Bs + wid * 2048;

  auto STAGE = [&](int bufw, int mt_, int k0e) {  // 8 VMEM ops per wave
    const int    lofs = bufw * 8192;
    const size_t ga   = (size_t)mt_ * (128 * Ln) + k0e;
#pragma unroll
    for (int j = 0; j < 4; ++j) {
      GLOAD_LDS16(gA + ga + (size_t)j * 8 * Ln, lA + lofs + j * 512);
      GLOAD_LDS16(gB + k0e + (size_t)j * 8 * Ln, lB + lofs + j * 512);
    }
  };

  // ---- hoisted epilogue constants (block-fixed; ~52 VGPR -- free at
  // LDS-limited 2 blocks/CU). Laundered address forces VMEM vector loads so
  // they stay in the vmcnt domain (oldest ops; drained by the first counted
  // wait, long since landed).
  int zero;
  asm volatile("v_mov_b32 %0, 0" : "=v"(zero));
  float4 b1q[2][2], w20q[2][2], w21q[2][2], b2q;
#pragma unroll
  for (int il = 0; il < 2; ++il) {
    const int i = bn * 4 + (wid & 1) * 2 + il;
#pragma unroll
    for (int q = 0; q < 2; ++q) {  // 12 x dwordx4
      const int hb = q * 16 + lq * 4 + zero;
      b1q[il][q]  = *reinterpret_cast<const float4*>(b1 + i * Hn + hb);
      w20q[il][q] = *reinterpret_cast<const float4*>(W2 + (i * 2 + 0) * Hn + hb);
      w21q[il][q] = *reinterpret_cast<const float4*>(W2 + (i * 2 + 1) * Hn + hb);
    }
  }
  b2q = *reinterpret_cast<const float4*>(b2 + (bn * 4 + (wid & 1) * 2) * 2 + zero);
  __builtin_amdgcn_sched_barrier(0);  // pin weight loads above the pipeline

  // ---- fragment reads: row = base + l15 (+f*16); linear slot = (ks2*4+lq) ^ (row&7)
  const int arow = (wid >> 1) * 64 + l15;
  const int brow = (wid & 1) * 64 + l15;
  const int swz7 = l15 & 7;

  f32x4 acc[4][4];  // acc[fn][fm]: rows = n-side (i,h), cols = batch
#pragma unroll
  for (int fn = 0; fn < 4; ++fn)
#pragma unroll
    for (int fm = 0; fm < 4; ++fm) acc[fn][fm] = f32x4{0.f, 0.f, 0.f, 0.f};

  auto COMPUTE = [&](int bufc) {
    const int cofs = bufc * 8192;
#pragma unroll
    for (int ks2 = 0; ks2 < 2; ++ks2) {
      const int se = ((ks2 * 4 + lq) ^ swz7) * 8;
      bf16x8 a[4], b[4];
#pragma unroll
      for (int f = 0; f < 4; ++f) {
        a[f] = *reinterpret_cast<const bf16x8*>(As + cofs + (arow + f * 16) * 64 + se);
        b[f] = *reinterpret_cast<const bf16x8*>(Bs + cofs + (brow + f * 16) * 64 + se);
      }
#pragma unroll
      for (int fn = 0; fn < 4; ++fn)
#pragma unroll
        for (int fm = 0; fm < 4; ++fm)
          acc[fn][fm] = __builtin_amdgcn_mfma_f32_16x16x32_bf16(b[fn], a[fm],
                                                                acc[fn][fm], 0, 0, 0);
    }
  };

  float* mus = out;
  float* lvs = out + (size_t)Bn * Ln;
  float* smp = out + (size_t)2 * Bn * Ln;

  int buf = 0;
  STAGE(0, 0, 0);

  for (int mt = 0; mt < MT; ++mt) {
    for (int k = 0; k < ksteps; ++k) {
      int kn = k + 1, mtn = mt;
      if (kn == ksteps) { kn = 0; ++mtn; }
      const bool epi  = (k == ksteps - 1);
      const bool more = (mtn < MT);

      // ---- epilogue pre-window: 1 eps load (all 256 lanes load tid&127's
      // row -> wave-uniform vmcnt counts), issued BEFORE the prefetch.
      float4 ep4;
      if (epi) {
        const size_t eo = (size_t)(mb + mt * 128 + (tid & 127)) * Ln + bn * 4;
        ep4 = *reinterpret_cast<const float4*>(eps + eo + zero);
        __builtin_amdgcn_sched_barrier(0);  // pin eps load above STAGE
      }

      if (more) {
        STAGE(buf ^ 1, mtn, kn * 64);  // 8 newest
        if (epi) asm volatile("s_waitcnt vmcnt(9)" ::: "memory");  // keep eps+8
        else     asm volatile("s_waitcnt vmcnt(8)" ::: "memory");  // keep 8
      } else {
        asm volatile("s_waitcnt vmcnt(1)" ::: "memory");           // keep eps
      }
      __builtin_amdgcn_s_barrier();
      __builtin_amdgcn_sched_barrier(0);  // pin ds_reads below the barrier
      COMPUTE(buf);

      if (epi) {
        // ======== per-m-tile epilogue: own scratch, ONE barrier total ========
        const int wrow = (wid >> 1) * 64;
#pragma unroll
        for (int il = 0; il < 2; ++il) {
          const int   icl   = (wid & 1) * 2 + il;
          const float bias0 = (il == 0) ? b2q.x : b2q.z;
          const float bias1 = (il == 0) ? b2q.y : b2q.w;
#pragma unroll
          for (int fm = 0; fm < 4; ++fm) {
            float p0 = 0.f, p1 = 0.f;
#pragma unroll
            for (int q = 0; q < 2; ++q) {
              const f32x4& A = acc[il * 2 + q][fm];
              const float* b1f = reinterpret_cast<const float*>(&b1q[il][q]);
              const float* w0f = reinterpret_cast<const float*>(&w20q[il][q]);
              const float* w1f = reinterpret_cast<const float*>(&w21q[il][q]);
#pragma unroll
              for (int r = 0; r < 4; ++r) {
                float x  = A[r] + b1f[r];
                float hv = fmaxf(x, 0.01f * x);  // leaky_relu (slope 0.01)
                p0 += hv * w0f[r];
                p1 += hv * w1f[r];
              }
            }
            p0 += __shfl_xor(p0, 16);
            p0 += __shfl_xor(p0, 32);
            p1 += __shfl_xor(p1, 16);
            p1 += __shfl_xor(p1, 32);
            if (lq == 0) {
              const int r = wrow + fm * 16 + l15;
              Sx[icl * 128 + r]       = p0 + bias0;
              Sx[512 + icl * 128 + r] = p1 + bias1;
            }
          }
        }
        // lgkmcnt(0) drains this wave's COMPUTE ds_reads AND its Sx writes;
        // the barrier then (a) makes Sx visible, (b) certifies all waves'
        // reads of As/Bs[buf] are done -> next STAGE may overwrite (this
        // replaces the loop-end barrier on epilogue iterations).
        asm volatile("s_waitcnt lgkmcnt(0)" ::: "memory");
        __builtin_amdgcn_s_barrier();

        if (tid < 128) {  // wave-uniform: waves 0,1 active
          const int    r = tid;
          const size_t o = (size_t)(mb + mt * 128 + r) * Ln + bn * 4;
          float4 muv, lvv;
          muv.x = Sx[r];       muv.y = Sx[128 + r]; muv.z = Sx[256 + r]; muv.w = Sx[384 + r];
          lvv.x = Sx[512 + r]; lvv.y = Sx[640 + r]; lvv.z = Sx[768 + r]; lvv.w = Sx[896 + r];
          float4 sm;
          sm.x = ep4.x * __builtin_exp2f(lvv.x * 0.7213475204444817f) + muv.x;
          sm.y = ep4.y * __builtin_exp2f(lvv.y * 0.7213475204444817f) + muv.y;
          sm.z = ep4.z * __builtin_exp2f(lvv.z * 0.7213475204444817f) + muv.z;
          sm.w = ep4.w * __builtin_exp2f(lvv.w * 0.7213475204444817f) + muv.w;
          *reinterpret_cast<float4*>(mus + o) = muv;
          *reinterpret_cast<float4*>(lvs + o) = lvv;
          *reinterpret_cast<float4*>(smp + o) = sm;
        }
        // reset accumulators for the next m-tile
#pragma unroll
        for (int fn = 0; fn < 4; ++fn)
#pragma unroll
          for (int fm = 0; fm < 4; ++fm) acc[fn][fm] = f32x4{0.f, 0.f, 0.f, 0.f};
      } else {
        __builtin_amdgcn_s_barrier();  // reads of buf done -> next STAGE may overwrite
      }
      buf ^= 1;
    }
  }
}

extern "C" void kernel_launch(void* const* d_in, const int* in_sizes, int n_in,
                              void* d_out, int out_size, void* d_ws, size_t ws_size,
                              hipStream_t stream) {
  const float* mu      = (const float*)d_in[0];
  const float* log_var = (const float*)d_in[1];
  const float* eps0    = (const float*)d_in[2];
  const float* eps     = (const float*)d_in[3];
  const float* W1      = (const float*)d_in[4];
  const float* b1      = (const float*)d_in[5];
  const float* W2      = (const float*)d_in[6];
  const float* b2      = (const float*)d_in[7];
  float* out = (float*)d_out;

  unsigned short* Vb  = (unsigned short*)d_ws;                                  // 4 MiB
  unsigned short* W1b = (unsigned short*)((char*)d_ws + (size_t)Bn * Ln * 2);   // 16 MiB

  prep_kernel<<<16384, 256, 0, stream>>>(W1, W1b, mu, log_var, eps0, Vb);
  gemm_fused_kernel<<<128 * (32 / MT), 256, 0, stream>>>(
      Vb, W1b, b1, W2, b2, eps, out);
}